// Round 1
// baseline (609.704 us; speedup 1.0000x reference)
//
#include <hip/hip_runtime.h>

#define NEG_INF (-1.0e30f)
#define T_BLOCK 256
#define K1_GRID 1024
#define K2_GRID 32

__device__ __forceinline__ bool pair_gt(float sa, int ia, float sb, int ib) {
    // strict total order: descending score, ascending index on ties (matches jax top_k)
    return (sa > sb) || (sa == sb && ia < ib);
}

template <int N, int T>
__device__ __forceinline__ void bitonic_sort_desc(float* ss, int* si) {
    const int tid = threadIdx.x;
    for (int k = 2; k <= N; k <<= 1) {
        for (int j = k >> 1; j > 0; j >>= 1) {
            __syncthreads();
            for (int i = tid; i < N; i += T) {
                int l = i ^ j;
                if (l > i) {
                    float s_i = ss[i], s_l = ss[l];
                    int   d_i = si[i], d_l = si[l];
                    bool sw = ((i & k) == 0) ? pair_gt(s_l, d_l, s_i, d_i)   // want descending: swap if a[l] > a[i]
                                             : pair_gt(s_i, d_i, s_l, d_l);  // want ascending:  swap if a[i] > a[l]
                    if (sw) { ss[i] = s_l; si[i] = d_l; ss[l] = s_i; si[l] = d_i; }
                }
            }
        }
    }
    __syncthreads();
}

// Pass 1: fused GEMV + per-block top-k.
// 16 lanes x float4 = one 256B row per lane-group; 16 rows per block-step.
__global__ __launch_bounds__(T_BLOCK) void k_score(const float* __restrict__ emb,
                                                   const int* __restrict__ p_idx,
                                                   int n_items,
                                                   float* __restrict__ cand_s,
                                                   int* __restrict__ cand_i,
                                                   int k) {
    __shared__ float ss[1024];
    __shared__ int   si[1024];
    const int tid = threadIdx.x;
    for (int i = tid; i < 1024; i += T_BLOCK) { ss[i] = NEG_INF; si[i] = 0x7fffffff; }

    const int   item_q = *p_idx;
    const int   col16  = tid & 15;   // which float4 of the row
    const int   grp    = tid >> 4;   // 0..15: which row within a block-step
    const float4 u4 = ((const float4*)(emb + (size_t)item_q * 64))[col16];

    const int groups_total = n_items >> 4;  // n_items divisible by 16 (1e6 = 16*62500)
    __syncthreads();

    int it = 0;
    for (int g = blockIdx.x; g < groups_total; g += gridDim.x, ++it) {
        const int item = g * 16 + grp;
        const float4 r = ((const float4*)(emb + (size_t)item * 64))[col16];
        float p = r.x * u4.x + r.y * u4.y + r.z * u4.z + r.w * u4.w;
        // sum across the 16 lanes holding this row
        p += __shfl_xor(p, 1, 16);
        p += __shfl_xor(p, 2, 16);
        p += __shfl_xor(p, 4, 16);
        p += __shfl_xor(p, 8, 16);
        if (col16 == 0) {
            const int s = it * 16 + grp;   // <= 61*16+15 = 991 < 1024 for grid=1024
            ss[s] = p;
            si[s] = item;
        }
    }

    bitonic_sort_desc<1024, T_BLOCK>(ss, si);

    if (tid < k) {
        cand_s[blockIdx.x * k + tid] = ss[tid];
        cand_i[blockIdx.x * k + tid] = si[tid];
    }
}

// Pass 2: reduce n_in candidates -> gridDim.x * k candidates
__global__ __launch_bounds__(T_BLOCK) void k_reduce(const float* __restrict__ cin_s,
                                                    const int* __restrict__ cin_i,
                                                    int n_in, int chunk,
                                                    float* __restrict__ cout_s,
                                                    int* __restrict__ cout_i,
                                                    int k) {
    __shared__ float ss[2048];
    __shared__ int   si[2048];
    const int tid  = threadIdx.x;
    const int base = blockIdx.x * chunk;
    for (int i = tid; i < 2048; i += T_BLOCK) {
        const int g = base + i;
        const bool v = (i < chunk) && (g < n_in);
        ss[i] = v ? cin_s[g] : NEG_INF;
        si[i] = v ? cin_i[g] : 0x7fffffff;
    }
    bitonic_sort_desc<2048, T_BLOCK>(ss, si);
    if (tid < k) {
        cout_s[blockIdx.x * k + tid] = ss[tid];
        cout_i[blockIdx.x * k + tid] = si[tid];
    }
}

// Pass 3: final single-block top-k, writes [k scores | k indices-as-float]
__global__ __launch_bounds__(T_BLOCK) void k_final(const float* __restrict__ cin_s,
                                                   const int* __restrict__ cin_i,
                                                   int n_in,
                                                   float* __restrict__ out,
                                                   int k) {
    __shared__ float ss[2048];
    __shared__ int   si[2048];
    const int tid = threadIdx.x;
    for (int i = tid; i < 2048; i += T_BLOCK) {
        const bool v = (i < n_in);
        ss[i] = v ? cin_s[i] : NEG_INF;
        si[i] = v ? cin_i[i] : 0x7fffffff;
    }
    bitonic_sort_desc<2048, T_BLOCK>(ss, si);
    if (tid < k) {
        out[tid]     = ss[tid];
        out[k + tid] = (float)si[tid];   // indices < 2^24: exact in fp32
    }
}

extern "C" void kernel_launch(void* const* d_in, const int* in_sizes, int n_in,
                              void* d_out, int out_size, void* d_ws, size_t ws_size,
                              hipStream_t stream) {
    const float* emb   = (const float*)d_in[0];
    const int*   p_idx = (const int*)d_in[1];
    const int n_items  = in_sizes[0] / 64;   // 1,000,000
    const int k        = out_size / 2;       // 50

    // workspace layout
    const int n1 = K1_GRID * k;              // 51200 candidates after pass 1
    const int n2 = K2_GRID * k;              // 1600 after pass 2
    float* cand_s = (float*)d_ws;
    int*   cand_i = (int*)(cand_s + n1);
    float* c2_s   = (float*)(cand_i + n1);
    int*   c2_i   = (int*)(c2_s + n2);

    k_score<<<K1_GRID, T_BLOCK, 0, stream>>>(emb, p_idx, n_items, cand_s, cand_i, k);
    const int chunk = (n1 + K2_GRID - 1) / K2_GRID;  // 1600 <= 2048
    k_reduce<<<K2_GRID, T_BLOCK, 0, stream>>>(cand_s, cand_i, n1, chunk, c2_s, c2_i, k);
    k_final<<<1, T_BLOCK, 0, stream>>>(c2_s, c2_i, n2, (float*)d_out, k);
}

// Round 2
// 368.456 us; speedup vs baseline: 1.6548x; 1.6548x over previous
//
#include <hip/hip_runtime.h>

#define NEG_INF (-1.0e30f)
#define CAP 4096          // candidate buffer capacity (expected ~230 for this data)
#define NBKT 4096         // 12-bit histogram buckets

__device__ __forceinline__ unsigned flip(float f) {
    // order-preserving map: larger float -> larger uint
    unsigned u = __float_as_uint(f);
    return (u & 0x80000000u) ? ~u : (u | 0x80000000u);
}

__device__ __forceinline__ bool pair_gt(float sa, int ia, float sb, int ib) {
    // descending score, ascending index on ties (matches jax.lax.top_k)
    return (sa > sb) || (sa == sb && ia < ib);
}

// ---------------- Pass 1: pure GEMV, scores[i] = emb[i] . emb[q] ----------------
// 16 lanes x float4 cover one 256B row; 4 rows per thread for load-level parallelism.
__global__ __launch_bounds__(256) void k_gemv(const float* __restrict__ emb,
                                              const int* __restrict__ p_idx,
                                              float* __restrict__ scores) {
    const int tid   = threadIdx.x;
    const int col16 = tid & 15;
    const int grp   = tid >> 4;
    const float4 u4 = ((const float4*)(emb + (size_t)(*p_idx) * 64))[col16];
    const int base  = blockIdx.x * 64;
#pragma unroll
    for (int sub = 0; sub < 4; ++sub) {
        const int item = base + sub * 16 + grp;
        const float4 r = ((const float4*)(emb + (size_t)item * 64))[col16];
        float p = r.x * u4.x + r.y * u4.y + r.z * u4.z + r.w * u4.w;
        p += __shfl_xor(p, 1, 16);
        p += __shfl_xor(p, 2, 16);
        p += __shfl_xor(p, 4, 16);
        p += __shfl_xor(p, 8, 16);
        if (col16 == 0) scores[item] = p;
    }
}

// ---------------- Pass 2: 4096-bucket histogram of key top-12-bits ----------------
__global__ __launch_bounds__(256) void k_hist(const float* __restrict__ scores,
                                              int n4, unsigned* __restrict__ hist) {
    __shared__ unsigned h[NBKT];
    const int tid = threadIdx.x;
    for (int i = tid; i < NBKT; i += 256) h[i] = 0;
    __syncthreads();
    const float4* s4 = (const float4*)scores;
    for (int i = blockIdx.x * 256 + tid; i < n4; i += gridDim.x * 256) {
        float4 v = s4[i];
        atomicAdd(&h[flip(v.x) >> 20], 1u);
        atomicAdd(&h[flip(v.y) >> 20], 1u);
        atomicAdd(&h[flip(v.z) >> 20], 1u);
        atomicAdd(&h[flip(v.w) >> 20], 1u);
    }
    __syncthreads();
    for (int i = tid; i < NBKT; i += 256) {
        unsigned c = h[i];
        if (c) atomicAdd(&hist[i], c);
    }
}

// ---------------- Pass 3: find boundary bucket B: C(B) < k <= C(B)+hist[B] ------
// C(b) = count of items in buckets strictly above b.
__global__ __launch_bounds__(256) void k_pick(const unsigned* __restrict__ hist,
                                              int k, unsigned* __restrict__ params) {
    __shared__ unsigned h[NBKT];
    __shared__ unsigned psum[256];
    const int tid = threadIdx.x;
    for (int i = tid; i < NBKT; i += 256) h[i] = hist[i];
    __syncthreads();
    const int base = tid * 16;
    unsigned local = 0;
#pragma unroll
    for (int j = 0; j < 16; ++j) local += h[base + j];
    psum[tid] = local;
    __syncthreads();
    // inclusive suffix-sum across threads: psum[t] = sum_{t' >= t} local[t']
    for (int stride = 1; stride < 256; stride <<= 1) {
        unsigned add = (tid + stride < 256) ? psum[tid + stride] : 0u;
        __syncthreads();
        psum[tid] += add;
        __syncthreads();
    }
    unsigned c = (tid + 1 < 256) ? psum[tid + 1] : 0u;  // items in buckets >= (tid+1)*16
    int found_b = -1; unsigned found_above = 0;
    for (int j = 15; j >= 0; --j) {
        unsigned hb = h[base + j];
        if (c < (unsigned)k && c + hb >= (unsigned)k) { found_b = base + j; found_above = c; }
        c += hb;
    }
    if (found_b >= 0) { params[0] = (unsigned)found_b; params[1] = found_above; }
}

// ---------------- Pass 4: append all items with bucket >= B ----------------------
__global__ __launch_bounds__(256) void k_compact(const float* __restrict__ scores,
                                                 int n4,
                                                 const unsigned* __restrict__ params,
                                                 unsigned* __restrict__ cnt,
                                                 float* __restrict__ cand_s,
                                                 int* __restrict__ cand_i) {
    const unsigned B = params[0];
    const float4* s4 = (const float4*)scores;
    for (int i = blockIdx.x * 256 + threadIdx.x; i < n4; i += gridDim.x * 256) {
        float4 v = s4[i];
        const float vv[4] = {v.x, v.y, v.z, v.w};
#pragma unroll
        for (int j = 0; j < 4; ++j) {
            if ((flip(vv[j]) >> 20) >= B) {
                unsigned pos = atomicAdd(cnt, 1u);
                if (pos < CAP) { cand_s[pos] = vv[j]; cand_i[pos] = i * 4 + j; }
            }
        }
    }
}

// ---------------- Pass 5: sort the ~230 candidates, emit top-k -------------------
__global__ __launch_bounds__(256) void k_final(const float* __restrict__ cand_s,
                                               const int* __restrict__ cand_i,
                                               const unsigned* __restrict__ cnt,
                                               int k, float* __restrict__ out) {
    __shared__ float ss[CAP];
    __shared__ int   si[CAP];
    const int tid = threadIdx.x;
    unsigned c = *cnt;
    const int n = (c > CAP) ? CAP : (int)c;
    int N = 64; while (N < n) N <<= 1;   // pow2 >= n (runtime-sized bitonic)
    for (int i = tid; i < N; i += 256) {
        const bool v = i < n;
        ss[i] = v ? cand_s[i] : NEG_INF;
        si[i] = v ? cand_i[i] : 0x7fffffff;
    }
    __syncthreads();
    for (int kk = 2; kk <= N; kk <<= 1) {
        for (int j = kk >> 1; j > 0; j >>= 1) {
            for (int i = tid; i < N; i += 256) {
                int l = i ^ j;
                if (l > i) {
                    float s_i = ss[i], s_l = ss[l];
                    int   d_i = si[i], d_l = si[l];
                    bool sw = ((i & kk) == 0) ? pair_gt(s_l, d_l, s_i, d_i)
                                              : pair_gt(s_i, d_i, s_l, d_l);
                    if (sw) { ss[i] = s_l; si[i] = d_l; ss[l] = s_i; si[l] = d_i; }
                }
            }
            __syncthreads();
        }
    }
    if (tid < k) {
        out[tid]     = ss[tid];
        out[k + tid] = (float)si[tid];   // indices < 2^24: exact in fp32
    }
}

extern "C" void kernel_launch(void* const* d_in, const int* in_sizes, int n_in,
                              void* d_out, int out_size, void* d_ws, size_t ws_size,
                              hipStream_t stream) {
    const float* emb   = (const float*)d_in[0];
    const int*   p_idx = (const int*)d_in[1];
    const int n_items  = in_sizes[0] / 64;   // 1,000,000
    const int k        = out_size / 2;       // 50

    // ws layout (4-byte units)
    float*    scores = (float*)d_ws;
    unsigned* hist   = (unsigned*)(scores + n_items);      // [NBKT]
    unsigned* params = hist + NBKT;                        // [0]=B, [1]=count_above
    unsigned* cnt    = params + 2;                         // candidate counter
    float*    cand_s = (float*)(cnt + 1);
    int*      cand_i = (int*)(cand_s + CAP);

    // zero hist + params + cnt in one async memset (graph-capture safe)
    hipMemsetAsync(hist, 0, (NBKT + 3) * sizeof(unsigned), stream);

    const int n4 = n_items / 4;
    k_gemv   <<<n_items / 64, 256, 0, stream>>>(emb, p_idx, scores);
    k_hist   <<<128, 256, 0, stream>>>(scores, n4, hist);
    k_pick   <<<1,   256, 0, stream>>>(hist, k, params);
    k_compact<<<128, 256, 0, stream>>>(scores, n4, params, cnt, cand_s, cand_i);
    k_final  <<<1,   256, 0, stream>>>(cand_s, cand_i, cnt, k, (float*)d_out);
}